// Round 3
// baseline (459.276 us; speedup 1.0000x reference)
//
#include <hip/hip_runtime.h>

// Element-wise 16-step spiking recurrence.
//   v = x; z = 0; out = 0
//   for t in 0..15: v -= z*h[t]; z = (v - T[t])/(|v|+1) > 0; out += z*d[t]
// |v|+1 > 0  =>  spike condition is exactly (v > T[t]) -> no divide.
// z in {0,1} so fmaf(-z,h,v) rounds identically to the reference's v - z*h.
//
// R3 change vs R2 (437 us, inferred kernel ~107 us vs 85 us copy floor):
//   PERSISTENT GRID-STRIDE + REGISTER PREFETCH.
//   R2's one-shot waves do load -> latency -> compute -> store -> die: the
//   load is in flight only once per wave lifetime, and the in-flight VMEM
//   pool drains at every block boundary. Persistent waves (2048 blocks,
//   guide G11) iterate 32x each, issuing iteration i+1's float4 load BEFORE
//   computing iteration i -> one load continuously in flight per wave on
//   top of 8-waves/SIMD TLP, same steady-state structure as the 6.29 TB/s
//   copy microbenchmark.
// Plain (non-NT) load/store kept per R2 A/B result.

typedef float floatv4 __attribute__((ext_vector_type(4)));

__global__ __launch_bounds__(256) void spike_recurrence_kernel(
    const float* __restrict__ x,
    const float* __restrict__ h,
    const float* __restrict__ d,
    const float* __restrict__ T,
    float* __restrict__ out,
    int n4)
{
    // Wave-uniform constant loads -> scalar loads into SGPRs.
    float hh[16], dd[16], tt[16];
#pragma unroll
    for (int t = 0; t < 16; ++t) {
        hh[t] = h[t];
        dd[t] = d[t];
        tt[t] = T[t];
    }

    const floatv4* __restrict__ x4 = reinterpret_cast<const floatv4*>(x);
    floatv4* __restrict__ o4 = reinterpret_cast<floatv4*>(out);

    int gtid    = blockIdx.x * blockDim.x + threadIdx.x;
    int gstride = gridDim.x * blockDim.x;   // 524288 threads -> 32 iters over n4

    // Prologue: first load in flight before entering the loop.
    floatv4 cur = {0.f, 0.f, 0.f, 0.f};
    if (gtid < n4) cur = x4[gtid];

    for (int i = gtid; i < n4; i += gstride) {
        // Issue next iteration's load BEFORE this iteration's compute:
        // its HBM latency hides under ~512 cycles of recurrence VALU.
        int inext = i + gstride;
        floatv4 nxt = {0.f, 0.f, 0.f, 0.f};
        if (inext < n4) nxt = x4[inext];

        float v[4], z[4], o[4];
#pragma unroll
        for (int j = 0; j < 4; ++j) {
            v[j] = cur[j];
            z[j] = 0.f;
            o[j] = 0.f;
        }
#pragma unroll
        for (int t = 0; t < 16; ++t) {
#pragma unroll
            for (int j = 0; j < 4; ++j) {
                v[j] = fmaf(-z[j], hh[t], v[j]);      // v -= z*h[t] (exact: z in {0,1})
                z[j] = (v[j] > tt[t]) ? 1.0f : 0.0f;  // sign((v-T)/(|v|+1)) == sign(v-T)
                o[j] = fmaf(z[j], dd[t], o[j]);       // out += z*d[t]
            }
        }
        floatv4 ov = {o[0], o[1], o[2], o[3]};
        o4[i] = ov;

        cur = nxt;
    }
}

extern "C" void kernel_launch(void* const* d_in, const int* in_sizes, int n_in,
                              void* d_out, int out_size, void* d_ws, size_t ws_size,
                              hipStream_t stream) {
    const float* x = (const float*)d_in[0];
    const float* h = (const float*)d_in[1];
    const float* d = (const float*)d_in[2];
    const float* T = (const float*)d_in[3];
    float* out = (float*)d_out;

    int n = in_sizes[0];          // 4*4096*4096 = 67,108,864 (divisible by 4)
    int n4 = n / 4;               // 16,777,216 float4 groups

    int block = 256;
    int grid = 2048;              // persistent: 8 blocks/CU x 256 CUs, 32 iters each
    spike_recurrence_kernel<<<grid, block, 0, stream>>>(x, h, d, T, out, n4);
}

// Round 4
// 434.683 us; speedup vs baseline: 1.0566x; 1.0566x over previous
//
#include <hip/hip_runtime.h>

// Element-wise 16-step spiking recurrence.
//   v = x; z = 0; out = 0
//   for t in 0..15: v -= z*h[t]; z = (v - T[t])/(|v|+1) > 0; out += z*d[t]
// |v|+1 > 0  =>  spike condition is exactly (v > T[t]) -> no divide.
//
// R4 change vs R2 (437 us; R3 persistent regressed to 459, reverted):
//   PACKED-FMA VALU CUT, bit-exact. Re-associate: o-update of step t and
//   v-update of step t+1 both use z_t, so fuse them into ONE v_pk_fma_f32:
//     {v, o} = fma({z_t, z_t}, {-h[t+1], d[t]}, {v, o})
//   with op_sel_hi:[0,1,1] broadcasting z (lo half of src0) to both lanes.
//   Per step per element: v_cmp + v_cndmask + v_pk_fma = 3 ops (was 4).
//   ~63 -> 48 VALU ops/element (-24%).
//   Exactness: z in {0,1} so z*h and z*d are exact products; each packed
//   lane rounds once, same as fmaf; accumulation order unchanged; the
//   dropped t=0 v-update is fma(-0,h,x)=x (sign-of-zero on v never
//   reaches out, which is built only from z*d).
// Memory structure identical to R2 (best): one-shot blocks, 2 float4/thread,
// plain (non-NT) loads/stores, 32768 blocks x 256 threads, exact cover.

typedef float floatv4 __attribute__((ext_vector_type(4)));
typedef float floatv2 __attribute__((ext_vector_type(2)));

__global__ __launch_bounds__(256) void spike_recurrence_kernel(
    const float* __restrict__ x,
    const float* __restrict__ h,
    const float* __restrict__ d,
    const float* __restrict__ T,
    float* __restrict__ out,
    int n4)
{
    // Wave-uniform constant loads -> scalar loads into SGPRs.
    // hd[t] = {-h[t+1], d[t]} feeds the packed FMA's B operand (one 64-bit
    // SGPR-pair source per instr -> within the 1-SGPR-operand rule).
    float tt[16];
    floatv2 hd[15];
#pragma unroll
    for (int t = 0; t < 16; ++t) tt[t] = T[t];
#pragma unroll
    for (int t = 0; t < 15; ++t) {
        hd[t].x = -h[t + 1];
        hd[t].y = d[t];
    }
    float d15 = d[15];

    const floatv4* __restrict__ x4 = reinterpret_cast<const floatv4*>(x);
    floatv4* __restrict__ o4 = reinterpret_cast<floatv4*>(out);

    // Two coalesced segments per block: [base, base+255] and [base+256, base+511].
    int base = blockIdx.x * (256 * 2) + threadIdx.x;
    int i0 = base;
    int i1 = base + 256;
    bool p0 = i0 < n4;
    bool p1 = i1 < n4;

    floatv4 xv0 = {0.f, 0.f, 0.f, 0.f};
    floatv4 xv1 = {0.f, 0.f, 0.f, 0.f};
    if (p0) xv0 = x4[i0];   // plain loads, issued before compute
    if (p1) xv1 = x4[i1];

    floatv2 vo[8];   // {v, o} per element, even-aligned VGPR pairs
    floatv2 zz[8];   // z in .x; .y present only to satisfy pair encoding
#pragma unroll
    for (int j = 0; j < 4; ++j) {
        vo[j]     = floatv2{xv0[j], 0.f};
        vo[4 + j] = floatv2{xv1[j], 0.f};
    }
#pragma unroll
    for (int j = 0; j < 8; ++j) {
        zz[j].x = (vo[j].x > tt[0]) ? 1.0f : 0.0f;   // z_0 = (x > T_0)
        zz[j].y = 0.f;
    }

#pragma unroll
    for (int t = 0; t < 15; ++t) {
#pragma unroll
        for (int j = 0; j < 8; ++j) {
            // vo.lo = fma(z, -h[t+1], v); vo.hi = fma(z, d[t], o)
            asm("v_pk_fma_f32 %0, %1, %2, %0 op_sel:[0,0,0] op_sel_hi:[0,1,1]"
                : "+v"(vo[j])
                : "v"(zz[j]), "s"(hd[t]));
            zz[j].x = (vo[j].x > tt[t + 1]) ? 1.0f : 0.0f;  // z_{t+1}
        }
    }

    float o[8];
#pragma unroll
    for (int j = 0; j < 8; ++j)
        o[j] = fmaf(zz[j].x, d15, vo[j].y);   // final: o += z_15 * d_15

    floatv4 ov0 = {o[0], o[1], o[2], o[3]};
    floatv4 ov1 = {o[4], o[5], o[6], o[7]};
    if (p0) o4[i0] = ov0;   // plain stores
    if (p1) o4[i1] = ov1;
}

extern "C" void kernel_launch(void* const* d_in, const int* in_sizes, int n_in,
                              void* d_out, int out_size, void* d_ws, size_t ws_size,
                              hipStream_t stream) {
    const float* x = (const float*)d_in[0];
    const float* h = (const float*)d_in[1];
    const float* d = (const float*)d_in[2];
    const float* T = (const float*)d_in[3];
    float* out = (float*)d_out;

    int n = in_sizes[0];          // 4*4096*4096 = 67,108,864 (divisible by 4)
    int n4 = n / 4;               // 16,777,216 float4 groups

    const int PER_BLOCK = 256 * 2;                  // 2 float4 per thread
    int block = 256;
    int grid = (n4 + PER_BLOCK - 1) / PER_BLOCK;    // 32768 blocks, exact cover
    spike_recurrence_kernel<<<grid, block, 0, stream>>>(x, h, d, T, out, n4);
}